// Round 1
// baseline (83.706 us; speedup 1.0000x reference)
//
#include <hip/hip_runtime.h>

#define SIREN_K 4
#define SIREN_H 32
#define SIREN_C 512
#define OMEGA0 30.0f

// ---------------------------------------------------------------------------
// Kernel 1: build the [K][C] SIREN filter table (tiny MLP, one block).
// pos: linspace(-1,1,K) * 30; h = sin(pos@w0.T+b0); h = sin(h@w1.T+b1);
// h = sin(h@w2.T+b2); ker[k][c] = h@w3.T + b3.
// ---------------------------------------------------------------------------
__global__ void siren_table_kernel(const float* __restrict__ w0, const float* __restrict__ b0,
                                   const float* __restrict__ w1, const float* __restrict__ b1,
                                   const float* __restrict__ w2, const float* __restrict__ b2,
                                   const float* __restrict__ w3, const float* __restrict__ b3,
                                   float* __restrict__ ker /* [K][C] */) {
    __shared__ float bufA[SIREN_K][SIREN_H];
    __shared__ float bufB[SIREN_K][SIREN_H];
    const int tid = threadIdx.x;

    // stage 0: h = sin(pos * w0 + b0)   (w0 is [H,1] -> flat [H])
    if (tid < SIREN_K * SIREN_H) {
        int k = tid >> 5, j = tid & 31;
        float pos = -1.0f + (2.0f / (float)(SIREN_K - 1)) * (float)k;
        if (k == SIREN_K - 1) pos = 1.0f;  // linspace hits endpoint exactly
        pos *= OMEGA0;
        bufA[k][j] = sinf(pos * w0[j] + b0[j]);
    }
    __syncthreads();

    // stage 1: h = sin(h @ w1.T + b1)
    if (tid < SIREN_K * SIREN_H) {
        int k = tid >> 5, j = tid & 31;
        float s = b1[j];
        #pragma unroll
        for (int i = 0; i < SIREN_H; ++i) s += bufA[k][i] * w1[j * SIREN_H + i];
        bufB[k][j] = sinf(s);
    }
    __syncthreads();

    // stage 2: h = sin(h @ w2.T + b2)   (write back into bufA)
    if (tid < SIREN_K * SIREN_H) {
        int k = tid >> 5, j = tid & 31;
        float s = b2[j];
        #pragma unroll
        for (int i = 0; i < SIREN_H; ++i) s += bufB[k][i] * w2[j * SIREN_H + i];
        bufA[k][j] = sinf(s);
    }
    __syncthreads();

    // stage 3: ker[k][c] = h @ w3.T + b3   (512 threads, one c each)
    const int c = tid;
    if (c < SIREN_C) {
        #pragma unroll
        for (int k = 0; k < SIREN_K; ++k) {
            float s = b3[c];
            #pragma unroll
            for (int j = 0; j < SIREN_H; ++j) s += bufA[k][j] * w3[c * SIREN_H + j];
            ker[k * SIREN_C + c] = s;
        }
    }
}

// ---------------------------------------------------------------------------
// Kernel 2: depthwise strided conv, fully vectorized float4 streaming.
// out[bl*512 + c] = sum_k x[(4*bl+k)*512 + c] * ker[k*512 + c]
// float4 view: out4[bl*128 + c4] = sum_k x4[(4*bl+k)*128 + c4] * ker4[k*128 + c4]
// blockDim=256 -> grid stride is a multiple of 128, so c4 is loop-invariant
// per thread and the 4 weight float4s stay in registers.
// ---------------------------------------------------------------------------
__global__ void __launch_bounds__(256) dwconv_kernel(const float4* __restrict__ x4,
                                                     const float4* __restrict__ ker4,
                                                     float4* __restrict__ out4,
                                                     int total4) {
    const int C4 = SIREN_C / 4;  // 128
    int idx = blockIdx.x * blockDim.x + threadIdx.x;
    const int gstride = gridDim.x * blockDim.x;  // multiple of 128
    const int c4 = idx & (C4 - 1);

    const float4 wv0 = ker4[0 * C4 + c4];
    const float4 wv1 = ker4[1 * C4 + c4];
    const float4 wv2 = ker4[2 * C4 + c4];
    const float4 wv3 = ker4[3 * C4 + c4];

    for (; idx < total4; idx += gstride) {
        const int bl = idx >> 7;  // idx / 128
        const float4* xp = x4 + (size_t)bl * (4 * C4) + c4;
        const float4 a = xp[0 * C4];
        const float4 b = xp[1 * C4];
        const float4 c = xp[2 * C4];
        const float4 d = xp[3 * C4];
        float4 o;
        o.x = a.x * wv0.x + b.x * wv1.x + c.x * wv2.x + d.x * wv3.x;
        o.y = a.y * wv0.y + b.y * wv1.y + c.y * wv2.y + d.y * wv3.y;
        o.z = a.z * wv0.z + b.z * wv1.z + c.z * wv2.z + d.z * wv3.z;
        o.w = a.w * wv0.w + b.w * wv1.w + c.w * wv2.w + d.w * wv3.w;
        out4[idx] = o;
    }
}

extern "C" void kernel_launch(void* const* d_in, const int* in_sizes, int n_in,
                              void* d_out, int out_size, void* d_ws, size_t ws_size,
                              hipStream_t stream) {
    // Input order (setup_inputs): x, w0, b0, w1, b1, w2, b2, w3, b3, target_len
    const float* x  = (const float*)d_in[0];
    const float* w0 = (const float*)d_in[1];
    const float* b0 = (const float*)d_in[2];
    const float* w1 = (const float*)d_in[3];
    const float* b1 = (const float*)d_in[4];
    const float* w2 = (const float*)d_in[5];
    const float* b2 = (const float*)d_in[6];
    const float* w3 = (const float*)d_in[7];
    const float* b3 = (const float*)d_in[8];

    float* ker = (float*)d_ws;  // K*C floats = 8 KiB

    siren_table_kernel<<<1, 512, 0, stream>>>(w0, b0, w1, b1, w2, b2, w3, b3, ker);

    const int total4 = out_size / 4;  // 8*4096*512/4 = 4,194,304 float4s
    const int blocks = 2048;          // grid-stride, 8 iters/thread
    dwconv_kernel<<<blocks, 256, 0, stream>>>((const float4*)x, (const float4*)ker,
                                              (float4*)d_out, total4);
}